// Round 14
// baseline (167.866 us; speedup 1.0000x reference)
//
#include <hip/hip_runtime.h>
#include <hip/hip_bf16.h>
#include <math.h>

#define HW    3136
#define WIMG  56
#define NPIX  25088   // 8 * 3136
#define CIN   128
#define RED   32
#define NGROUP 8
#define GCH   16
#define KKK   49
#define TP    32      // pixels per block

typedef __attribute__((ext_vector_type(8))) short short8;
typedef __attribute__((ext_vector_type(4))) float f32x4;
typedef unsigned short ushort_t;

static __device__ __forceinline__ unsigned int f2b(float f) {
    union { __hip_bfloat16 b; unsigned short u; } cv;
    cv.b = __float2bfloat16(f);
    return (unsigned int)cv.u;
}

// tanh-form GELU (validated rounds 7-13: absmax 0.031)
static __device__ __forceinline__ float gelu_t(float h) {
    float z = h * fmaf(0.0356774081f, h * h, 0.7978845608f);
    float e = __expf(-2.f * z);
    return __fdividef(h, 1.f + e);
}

// ---------------- k_prep: weight conversions ----------------
__global__ __launch_bounds__(256) void k_prep(const float* __restrict__ conv1_w,
    const float* __restrict__ conv1_b, const float* __restrict__ bn_g,
    const float* __restrict__ bn_b, const float* __restrict__ bn_m,
    const float* __restrict__ bn_v, const float* __restrict__ conv2_w,
    const float* __restrict__ ln_w, const float* __restrict__ w1,
    const float* __restrict__ w2,
    ushort_t* __restrict__ c1b, ushort_t* __restrict__ c2b,
    ushort_t* __restrict__ lw1b, ushort_t* __restrict__ w2b,
    float* __restrict__ sc1, float* __restrict__ sh1)
{
    int id = blockIdx.x * 256 + threadIdx.x;     // 0..65535
    w2b[id] = (ushort_t)f2b(w2[id]);
    int c = id & 127;
    lw1b[id] = (ushort_t)f2b(w1[id] * ln_w[c]);
    if (id < 4096)  c1b[id] = (ushort_t)f2b(conv1_w[id]);
    if (id < 12800) c2b[id] = (id < 12544) ? (ushort_t)f2b(conv2_w[id]) : (ushort_t)0;
    if (id < 32) {
        float sc = bn_g[id] * rsqrtf(bn_v[id] + 1e-5f);
        sc1[id] = sc;
        sh1[id] = (conv1_b[id] - bn_m[id]) * sc + bn_b[id];
    }
}

// s1[n] = sum_c ln_w[c]*w1[n,c]; t1[n] = sum_c ln_b[c]*w1[n,c] + b1[n]
__global__ void k_prep2(const float* __restrict__ w1, const float* __restrict__ ln_w,
    const float* __restrict__ ln_b, const float* __restrict__ b1,
    float* __restrict__ s1, float* __restrict__ t1)
{
    int n = threadIdx.x;   // 512
    const float* wr = w1 + (size_t)n * 128;
    float s = 0.f, t = 0.f;
    #pragma unroll 8
    for (int c = 0; c < 128; ++c) { float w = wr[c]; s += ln_w[c] * w; t += ln_b[c] * w; }
    s1[n] = s; t1[n] = t + b1[n];
}

// ---------------- k_mega: conv1+BN+ReLU+conv2 -> involution -> LN -> MLP -> +res ----------------
// block = 32 pixels, grid 784, per-image XCD swizzle. LDS overlay (45,120 B -> 3 blocks/CU):
//   [0     , 27200) swg[400][34] bf16 (A out / B in) == sh[32][136] (phase C)
//   [27200 , 35904) sx [32][136] bf16 (A: x tile; B out / C in: inv tile)
//   [35904 , 45120) st[32][40] bf16 (A) == sred/sred2[32][36] f32 (B/C)
__global__ __launch_bounds__(256) void k_mega(const float* __restrict__ x,
    const short* __restrict__ c1b, const short* __restrict__ c2b,
    const float* __restrict__ sc1, const float* __restrict__ sh1,
    const float* __restrict__ c2bias,
    const ushort_t* __restrict__ lw1b, const ushort_t* __restrict__ w2b,
    const float* __restrict__ s1, const float* __restrict__ t1,
    const float* __restrict__ b2, float* __restrict__ outp)
{
    __shared__ __align__(16) char smem[45120];
    short* swg  = (short*)smem;                    // [400][34]
    short* sh   = (short*)smem;                    // overlay, [32][136] (phase C)
    short* sx   = (short*)(smem + 27200);          // [32][136]
    short* st   = (short*)(smem + 35904);          // [32][40] (phase A)
    float* sred  = (float*)(smem + 35904);         // [32][36] (phase B+)
    float* sred2 = sred + 1152;

    int tid  = threadIdx.x;
    int bid  = blockIdx.x;
    // per-image XCD swizzle: xcd (bid&7) gets image bid&7's 98 consecutive tiles
    int sblk = (bid & 7) * 98 + (bid >> 3);
    int P0   = sblk * TP;
    int b    = P0 / HW;
    int p0i  = P0 - b * HW;
    int lane = tid & 63, wv = tid >> 6;
    int ln15 = lane & 15, quad = lane >> 4;

    // ======== Phase A0: stage x -> sx (bf16 [px][c], stride 136) ========
    const float* xb = x + (size_t)b * CIN * HW + p0i;
    #pragma unroll
    for (int it = 0; it < 16; ++it) {
        int idx = it * 256 + tid;        // 0..4095
        int c = idx >> 5, pp = idx & 31;
        sx[pp * 136 + c] = (short)f2b(xb[(size_t)c * HW + pp]);
    }
    __syncthreads();

    // ======== Phase A1: conv1 + BN + ReLU -> st (cooperative) ========
    {
        int mt = wv & 1, nt = wv >> 1;   // wave: px-half x out-half
        f32x4 a1 = (f32x4)0.f;
        #pragma unroll
        for (int kc = 0; kc < 128; kc += 32) {
            short8 af = *(const short8*)&sx[(mt * 16 + ln15) * 136 + kc + quad * 8];
            short8 bf = *(const short8*)&c1b[(size_t)(nt * 16 + ln15) * 128 + kc + quad * 8];
            a1 = __builtin_amdgcn_mfma_f32_16x16x32_bf16(af, bf, a1, 0, 0, 0);
        }
        int o = nt * 16 + ln15;
        float sc = sc1[o], shv = sh1[o];
        #pragma unroll
        for (int r = 0; r < 4; ++r) {
            float tv = fmaxf(a1[r] * sc + shv, 0.f);
            st[(mt * 16 + quad * 4 + r) * 40 + o] = (short)f2b(tv);
        }
    }
    __syncthreads();

    // ======== Phase A2: conv2 -> swg (LDS, [gk][px] stride 34) ========
    {
        short8 af2[2];
        #pragma unroll
        for (int mt = 0; mt < 2; ++mt)
            af2[mt] = *(const short8*)&st[(mt * 16 + ln15) * 40 + quad * 8];
        f32x4 zc = (f32x4)0.f;
        for (int nt = wv; nt < 25; nt += 4) {
            int gk = nt * 16 + ln15;
            short8 bf2 = *(const short8*)&c2b[(size_t)gk * 32 + quad * 8];
            float bj = (gk < 392) ? c2bias[gk] : 0.f;
            #pragma unroll
            for (int mt = 0; mt < 2; ++mt) {
                f32x4 a2 = __builtin_amdgcn_mfma_f32_16x16x32_bf16(af2[mt], bf2, zc, 0, 0, 0);
                uint2 pk;
                pk.x = f2b(a2[0] + bj) | (f2b(a2[1] + bj) << 16);
                pk.y = f2b(a2[2] + bj) | (f2b(a2[3] + bj) << 16);
                *(uint2*)&swg[gk * 34 + mt * 16 + quad * 4] = pk;
            }
        }
    }
    __syncthreads();   // swg complete; sx + st free to overwrite

    // ======== Phase B: involution gather; inv -> sx; LN partials -> sred ========
    {
        int q   = tid & 7;           // px quad (0..7)
        int gy  = tid >> 3;          // ch slice (0..31): 4 channels each
        int g   = gy >> 2;
        int sub = gy & 3;
        int pl0 = q * 4;
        int p   = p0i + pl0;
        int prow = p / WIMG;
        int pcol = p - prow * WIMG;  // multiple of 4 (4 | 56 -> quad never straddles a row)
        const float* xc = x + ((size_t)b * CIN + g * GCH + sub * 4) * HW;
        float acc[4][4];
        #pragma unroll
        for (int i = 0; i < 4; ++i)
            #pragma unroll
            for (int c = 0; c < 4; ++c) acc[i][c] = 0.f;
        bool c_lo = (pcol >= 4);
        bool c_hi = (pcol <= 48);
        #pragma unroll
        for (int dy = -3; dy <= 3; ++dy) {
            int grow = prow + dy;
            if (grow < 0 || grow >= WIMG) continue;
            float wkf[7][4];
            #pragma unroll
            for (int dx = 0; dx < 7; ++dx) {
                int gk = g * KKK + (dy + 3) * 7 + dx;
                uint2 wld = *(const uint2*)&swg[gk * 34 + pl0];
                wkf[dx][0] = __uint_as_float(wld.x << 16);
                wkf[dx][1] = __uint_as_float(wld.x & 0xffff0000u);
                wkf[dx][2] = __uint_as_float(wld.y << 16);
                wkf[dx][3] = __uint_as_float(wld.y & 0xffff0000u);
            }
            const float* xrow = xc + grow * WIMG + pcol;
            #pragma unroll
            for (int c = 0; c < 4; ++c) {
                const float* xr = xrow + (size_t)c * HW;
                float4 v0 = c_lo ? *(const float4*)(xr - 4) : make_float4(0.f,0.f,0.f,0.f);
                float4 v1 = *(const float4*)(xr);
                float4 v2 = c_hi ? *(const float4*)(xr + 4) : make_float4(0.f,0.f,0.f,0.f);
                float vv[12] = {v0.x,v0.y,v0.z,v0.w, v1.x,v1.y,v1.z,v1.w, v2.x,v2.y,v2.z,v2.w};
                #pragma unroll
                for (int dx = 0; dx < 7; ++dx)
                    #pragma unroll
                    for (int i = 0; i < 4; ++i)
                        acc[i][c] += wkf[dx][i] * vv[i + dx + 1];
            }
        }
        #pragma unroll
        for (int i = 0; i < 4; ++i) {
            float s = 0.f, s2 = 0.f;
            #pragma unroll
            for (int c = 0; c < 4; ++c) { s += acc[i][c]; s2 += acc[i][c] * acc[i][c]; }
            uint2 pk;
            pk.x = f2b(acc[i][0]) | (f2b(acc[i][1]) << 16);
            pk.y = f2b(acc[i][2]) | (f2b(acc[i][3]) << 16);
            *(uint2*)&sx[(pl0 + i) * 136 + g * GCH + sub * 4] = pk;
            sred [(pl0 + i) * 36 + gy] = s;
            sred2[(pl0 + i) * 36 + gy] = s2;
        }
    }
    __syncthreads();   // inv tile + partials complete — LAST pre-C barrier

    // ======== Phase C: MLP (4 hidden chunks of 128) ========
    // per-lane LN stats straight from sred (no reduction barrier; stride 36 -> 16B-aligned)
    float mu_r[2], rs_r[2];
    #pragma unroll
    for (int tn = 0; tn < 2; ++tn) {
        int px = tn * 16 + ln15;
        float s = 0.f, s2 = 0.f;
        #pragma unroll
        for (int k4 = 0; k4 < 8; ++k4) {
            float4 a = *(const float4*)&sred [px * 36 + k4 * 4];
            float4 c = *(const float4*)&sred2[px * 36 + k4 * 4];
            s  += a.x + a.y + a.z + a.w;
            s2 += c.x + c.y + c.z + c.w;
        }
        float m = s * (1.f / 128.f);
        mu_r[tn] = m;
        rs_r[tn] = rsqrtf(s2 * (1.f / 128.f) - m * m + 1e-6f);
    }

    f32x4 acc2[2][2];
    #pragma unroll
    for (int i = 0; i < 2; ++i)
        #pragma unroll
        for (int j = 0; j < 2; ++j) acc2[i][j] = (f32x4)0.f;

    for (int j = 0; j < 4; ++j) {
        // bulk prefetch: all 16 global weight fragments for this chunk in flight at once
        short8 a1f[4][2], b2f[4][2];
        #pragma unroll
        for (int k4 = 0; k4 < 4; ++k4) {
            #pragma unroll
            for (int tm = 0; tm < 2; ++tm)
                a1f[k4][tm] = *(const short8*)&lw1b[(size_t)(j * 128 + wv * 32 + tm * 16 + ln15) * 128 + k4 * 32 + quad * 8];
            #pragma unroll
            for (int tn = 0; tn < 2; ++tn)
                b2f[k4][tn] = *(const short8*)&w2b[(size_t)(wv * 32 + tn * 16 + ln15) * 512 + j * 128 + k4 * 32 + quad * 8];
        }
        // phase 1: H chunk [128 n x 32 px]; wave wv owns n-rows wv*32..+32
        f32x4 acc1[2][2];
        #pragma unroll
        for (int tm = 0; tm < 2; ++tm)
            #pragma unroll
            for (int tn = 0; tn < 2; ++tn) acc1[tm][tn] = (f32x4)0.f;
        #pragma unroll
        for (int k4 = 0; k4 < 4; ++k4) {
            short8 bf[2];
            #pragma unroll
            for (int tn = 0; tn < 2; ++tn)
                bf[tn] = *(const short8*)&sx[(tn * 16 + ln15) * 136 + k4 * 32 + quad * 8];
            #pragma unroll
            for (int tm = 0; tm < 2; ++tm)
                #pragma unroll
                for (int tn = 0; tn < 2; ++tn)
                    acc1[tm][tn] = __builtin_amdgcn_mfma_f32_16x16x32_bf16(a1f[k4][tm], bf[tn], acc1[tm][tn], 0, 0, 0);
        }
        // LN + GELU -> sh (overlays dead swg)
        #pragma unroll
        for (int tm = 0; tm < 2; ++tm) {
            int nl = wv * 32 + tm * 16 + quad * 4;
            int n  = j * 128 + nl;
            float4 s14 = *(const float4*)&s1[n];
            float4 t14 = *(const float4*)&t1[n];
            #pragma unroll
            for (int tn = 0; tn < 2; ++tn) {
                int px = tn * 16 + ln15;
                float g0 = gelu_t(rs_r[tn] * (acc1[tm][tn][0] - mu_r[tn] * s14.x) + t14.x);
                float g1 = gelu_t(rs_r[tn] * (acc1[tm][tn][1] - mu_r[tn] * s14.y) + t14.y);
                float g2 = gelu_t(rs_r[tn] * (acc1[tm][tn][2] - mu_r[tn] * s14.z) + t14.z);
                float g3 = gelu_t(rs_r[tn] * (acc1[tm][tn][3] - mu_r[tn] * s14.w) + t14.w);
                uint2 pk;
                pk.x = f2b(g0) | (f2b(g1) << 16);
                pk.y = f2b(g2) | (f2b(g3) << 16);
                *(uint2*)&sh[px * 136 + nl] = pk;
            }
        }
        __syncthreads();   // H chunk complete
        // phase 2: acc2[32 px x 128 c] += H . w2chunk^T (b2f long since landed)
        #pragma unroll
        for (int k4 = 0; k4 < 4; ++k4) {
            short8 af[2];
            #pragma unroll
            for (int tm = 0; tm < 2; ++tm)
                af[tm] = *(const short8*)&sh[(tm * 16 + ln15) * 136 + k4 * 32 + quad * 8];
            #pragma unroll
            for (int tm = 0; tm < 2; ++tm)
                #pragma unroll
                for (int tn = 0; tn < 2; ++tn)
                    acc2[tm][tn] = __builtin_amdgcn_mfma_f32_16x16x32_bf16(af[tm], b2f[k4][tn], acc2[tm][tn], 0, 0, 0);
        }
        __syncthreads();   // before next chunk rewrites sh
    }

    // ======== final epilogue: +b2 +residual, fp32 channels-first float4 ========
    #pragma unroll
    for (int tm = 0; tm < 2; ++tm) {
        int p = p0i + tm * 16 + quad * 4;
        #pragma unroll
        for (int tn = 0; tn < 2; ++tn) {
            int c = wv * 32 + tn * 16 + ln15;
            size_t base = ((size_t)b * CIN + c) * HW + p;
            float bj = b2[c];
            float4 rv = *(const float4*)&x[base];
            float4 ov = make_float4(acc2[tm][tn][0] + bj + rv.x,
                                    acc2[tm][tn][1] + bj + rv.y,
                                    acc2[tm][tn][2] + bj + rv.z,
                                    acc2[tm][tn][3] + bj + rv.w);
            *(float4*)&outp[base] = ov;
        }
    }
}

extern "C" void kernel_launch(void* const* d_in, const int* in_sizes, int n_in,
                              void* d_out, int out_size, void* d_ws, size_t ws_size,
                              hipStream_t stream) {
    const float* x       = (const float*)d_in[0];
    const float* conv1_w = (const float*)d_in[1];
    const float* conv1_b = (const float*)d_in[2];
    const float* bn_g    = (const float*)d_in[3];
    const float* bn_b    = (const float*)d_in[4];
    const float* bn_m    = (const float*)d_in[5];
    const float* bn_v    = (const float*)d_in[6];
    const float* conv2_w = (const float*)d_in[7];
    const float* conv2_b = (const float*)d_in[8];
    const float* ln_w    = (const float*)d_in[9];
    const float* ln_b    = (const float*)d_in[10];
    const float* w1      = (const float*)d_in[11];
    const float* b1      = (const float*)d_in[12];
    const float* w2      = (const float*)d_in[13];
    const float* b2      = (const float*)d_in[14];
    float* out = (float*)d_out;

    float* F = (float*)d_ws;
    float* sc1  = F;                 // 32
    float* sh1  = F + 32;            // 32
    float* s1   = F + 64;            // 512
    float* t1   = F + 576;           // 512
    ushort_t* S    = (ushort_t*)(F + 1088);
    ushort_t* c1b  = S;              // 4096
    ushort_t* c2b  = c1b + 4096;     // 12800 (400x32, zero-padded)
    ushort_t* lw1b = c2b + 12800;    // 65536
    ushort_t* w2b  = lw1b + 65536;   // 65536

    k_prep <<<256, 256, 0, stream>>>(conv1_w, conv1_b, bn_g, bn_b, bn_m, bn_v,
                                     conv2_w, ln_w, w1, w2, c1b, c2b, lw1b, w2b, sc1, sh1);
    k_prep2<<<1, 512, 0, stream>>>(w1, ln_w, ln_b, b1, s1, t1);
    k_mega <<<784, 256, 0, stream>>>(x, (const short*)c1b, (const short*)c2b,
                                     sc1, sh1, conv2_b, lw1b, w2b, s1, t1, b2, out);
}

// Round 15
// 147.361 us; speedup vs baseline: 1.1391x; 1.1391x over previous
//
#include <hip/hip_runtime.h>
#include <hip/hip_bf16.h>
#include <math.h>

#define HW    3136
#define WIMG  56
#define NPIX  25088   // 8 * 3136
#define CIN   128
#define RED   32
#define NGROUP 8
#define GCH   16
#define KKK   49

typedef __attribute__((ext_vector_type(8))) short short8;
typedef __attribute__((ext_vector_type(4))) float f32x4;
typedef unsigned short ushort_t;

static __device__ __forceinline__ unsigned int f2b(float f) {
    union { __hip_bfloat16 b; unsigned short u; } cv;
    cv.b = __float2bfloat16(f);
    return (unsigned int)cv.u;
}

// tanh-form GELU (validated rounds 7-14: absmax 0.031)
static __device__ __forceinline__ float gelu_t(float h) {
    float z = h * fmaf(0.0356774081f, h * h, 0.7978845608f);
    float e = __expf(-2.f * z);
    return __fdividef(h, 1.f + e);
}

// ---------------- k_prep: weight conversions ----------------
__global__ __launch_bounds__(256) void k_prep(const float* __restrict__ conv1_w,
    const float* __restrict__ conv1_b, const float* __restrict__ bn_g,
    const float* __restrict__ bn_b, const float* __restrict__ bn_m,
    const float* __restrict__ bn_v, const float* __restrict__ conv2_w,
    const float* __restrict__ ln_w, const float* __restrict__ w1,
    const float* __restrict__ w2,
    ushort_t* __restrict__ c1b, ushort_t* __restrict__ c2b,
    ushort_t* __restrict__ lw1b, ushort_t* __restrict__ w2b,
    float* __restrict__ sc1, float* __restrict__ sh1)
{
    int id = blockIdx.x * 256 + threadIdx.x;     // 0..65535
    w2b[id] = (ushort_t)f2b(w2[id]);
    int c = id & 127;
    lw1b[id] = (ushort_t)f2b(w1[id] * ln_w[c]);
    if (id < 4096)  c1b[id] = (ushort_t)f2b(conv1_w[id]);
    if (id < 12800) c2b[id] = (id < 12544) ? (ushort_t)f2b(conv2_w[id]) : (ushort_t)0;
    if (id < 32) {
        float sc = bn_g[id] * rsqrtf(bn_v[id] + 1e-5f);
        sc1[id] = sc;
        sh1[id] = (conv1_b[id] - bn_m[id]) * sc + bn_b[id];
    }
}

// s1[n] = sum_c ln_w[c]*w1[n,c]; t1[n] = sum_c ln_b[c]*w1[n,c] + b1[n]
__global__ void k_prep2(const float* __restrict__ w1, const float* __restrict__ ln_w,
    const float* __restrict__ ln_b, const float* __restrict__ b1,
    float* __restrict__ s1, float* __restrict__ t1)
{
    int n = threadIdx.x;   // 512
    const float* wr = w1 + (size_t)n * 128;
    float s = 0.f, t = 0.f;
    #pragma unroll 8
    for (int c = 0; c < 128; ++c) { float w = wr[c]; s += ln_w[c] * w; t += ln_b[c] * w; }
    s1[n] = s; t1[n] = t + b1[n];
}

// ---------------- k_mega: conv1+BN+ReLU+conv2 -> involution -> LN -> MLP -> +res ----------------
// block = 64 pixels, grid 392, XCD-swizzled. LDS overlay (80,960 B -> 2 blocks/CU):
//   [0      , 53312) swg[392][68] bf16 (A out / B in) == sh0[64][136] + sh1[64][136] (phase C dbuf)
//   [53312  , 70720) sx [64][136] bf16 (A: x tile; B out / C in: inv tile)
//   [70720  , 80960) st [64][40] bf16 (A)  ==  sred/sred2[64][20] f32 (B/C)
__global__ __launch_bounds__(256, 2) void k_mega(const float* __restrict__ x,
    const short* __restrict__ c1b, const short* __restrict__ c2b,
    const float* __restrict__ sc1, const float* __restrict__ sh1,
    const float* __restrict__ c2bias,
    const ushort_t* __restrict__ lw1b, const ushort_t* __restrict__ w2b,
    const float* __restrict__ s1, const float* __restrict__ t1,
    const float* __restrict__ b2, float* __restrict__ outp)
{
    __shared__ __align__(16) char smem[80960];
    short* swg  = (short*)smem;                    // [392][68]
    short* sh0  = (short*)smem;                    // phase C dbuf 0, [64][136]
    short* sh1b = (short*)smem + 8704;             // phase C dbuf 1, [64][136]
    short* sx   = (short*)smem + 26656;            // [64][136]
    short* st   = (short*)(smem + 70720);          // [64][40] (phase A only)
    float* sred  = (float*)(smem + 70720);         // [64][20] (phase B+)
    float* sred2 = sred + 1280;

    int tid  = threadIdx.x;
    int bid  = blockIdx.x;
    // XCD swizzle: consecutive tiles of one image land on one XCD (round-robin dispatch)
    int sblk = (bid & 7) * 49 + (bid >> 3);
    int P0   = sblk * 64;
    int b    = P0 / HW;
    int p0i  = P0 - b * HW;
    int lane = tid & 63, wv = tid >> 6;
    int ln15 = lane & 15, quad = lane >> 4;

    // ======== Phase A0: stage x -> sx (bf16 [px][c], stride 136) ========
    const float* xb = x + (size_t)b * CIN * HW + p0i;
    #pragma unroll
    for (int it = 0; it < 32; ++it) {
        int idx = it * 256 + tid;
        int c = idx >> 6, pp = idx & 63;
        sx[pp * 136 + c] = (short)f2b(xb[(size_t)c * HW + pp]);
    }
    __syncthreads();

    // ======== Phase A1: conv1 + BN + ReLU -> st (wave-private rows) ========
    f32x4 acc1c[2] = {(f32x4)0.f, (f32x4)0.f};
    #pragma unroll
    for (int kc = 0; kc < 128; kc += 32) {
        short8 af = *(const short8*)&sx[(wv * 16 + ln15) * 136 + kc + quad * 8];
        #pragma unroll
        for (int nt = 0; nt < 2; ++nt) {
            short8 bf = *(const short8*)&c1b[(size_t)(nt * 16 + ln15) * 128 + kc + quad * 8];
            acc1c[nt] = __builtin_amdgcn_mfma_f32_16x16x32_bf16(af, bf, acc1c[nt], 0, 0, 0);
        }
    }
    #pragma unroll
    for (int nt = 0; nt < 2; ++nt) {
        int o = nt * 16 + ln15;
        float sc = sc1[o], shv = sh1[o];
        #pragma unroll
        for (int r = 0; r < 4; ++r) {
            float tv = fmaxf(acc1c[nt][r] * sc + shv, 0.f);
            st[(wv * 16 + quad * 4 + r) * 40 + o] = (short)f2b(tv);
        }
    }
    // ======== Phase A2: conv2 -> swg (LDS); bulk-prefetch the 25 weight frags ========
    {
        short8 af2 = *(const short8*)&st[(wv * 16 + ln15) * 40 + quad * 8];
        short8 bf2[25];
        #pragma unroll
        for (int nt = 0; nt < 25; ++nt)
            bf2[nt] = *(const short8*)&c2b[(size_t)(nt * 16 + ln15) * 32 + quad * 8];
        f32x4 zc = (f32x4)0.f;
        #pragma unroll
        for (int nt = 0; nt < 25; ++nt) {
            int gk = nt * 16 + ln15;
            f32x4 a2 = __builtin_amdgcn_mfma_f32_16x16x32_bf16(af2, bf2[nt], zc, 0, 0, 0);
            if (gk < 392) {
                float bj = c2bias[gk];
                uint2 pk;
                pk.x = f2b(a2[0] + bj) | (f2b(a2[1] + bj) << 16);
                pk.y = f2b(a2[2] + bj) | (f2b(a2[3] + bj) << 16);
                *(uint2*)&swg[gk * 68 + wv * 16 + quad * 4] = pk;
            }
        }
    }
    __syncthreads();   // swg complete; sx (x-tile) free to overwrite; st dead

    // ======== Phase B: involution gather; inv -> sx; LN partials -> sred ========
    {
        int q   = tid & 15;          // px quad
        int gy  = tid >> 4;          // 0..15
        int g   = gy >> 1;
        int sub = gy & 1;
        int pl0 = q * 4;
        int p   = p0i + pl0;
        int prow = p / WIMG;
        int pcol = p - prow * WIMG;  // multiple of 4 (4 | 56 -> quad never straddles a row)
        const float* xc = x + ((size_t)b * CIN + g * GCH + sub * 8) * HW;
        float acc[4][8];
        #pragma unroll
        for (int i = 0; i < 4; ++i)
            #pragma unroll
            for (int c = 0; c < 8; ++c) acc[i][c] = 0.f;
        bool c_lo = (pcol >= 4);
        bool c_hi = (pcol <= 48);
        #pragma unroll
        for (int dy = -3; dy <= 3; ++dy) {
            int grow = prow + dy;
            if (grow < 0 || grow >= WIMG) continue;
            float wkf[7][4];
            #pragma unroll
            for (int dx = 0; dx < 7; ++dx) {
                int gk = g * KKK + (dy + 3) * 7 + dx;
                uint2 wld = *(const uint2*)&swg[gk * 68 + pl0];
                wkf[dx][0] = __uint_as_float(wld.x << 16);
                wkf[dx][1] = __uint_as_float(wld.x & 0xffff0000u);
                wkf[dx][2] = __uint_as_float(wld.y << 16);
                wkf[dx][3] = __uint_as_float(wld.y & 0xffff0000u);
            }
            const float* xrow = xc + grow * WIMG + pcol;
            #pragma unroll
            for (int c = 0; c < 8; ++c) {
                const float* xr = xrow + (size_t)c * HW;
                float4 v0 = c_lo ? *(const float4*)(xr - 4) : make_float4(0.f,0.f,0.f,0.f);
                float4 v1 = *(const float4*)(xr);
                float4 v2 = c_hi ? *(const float4*)(xr + 4) : make_float4(0.f,0.f,0.f,0.f);
                float vv[12] = {v0.x,v0.y,v0.z,v0.w, v1.x,v1.y,v1.z,v1.w, v2.x,v2.y,v2.z,v2.w};
                #pragma unroll
                for (int dx = 0; dx < 7; ++dx)
                    #pragma unroll
                    for (int i = 0; i < 4; ++i)
                        acc[i][c] += wkf[dx][i] * vv[i + dx + 1];
            }
        }
        #pragma unroll
        for (int i = 0; i < 4; ++i) {
            unsigned pk[4];
            float s = 0.f, s2 = 0.f;
            #pragma unroll
            for (int h = 0; h < 4; ++h)
                pk[h] = f2b(acc[i][2*h]) | (f2b(acc[i][2*h+1]) << 16);
            #pragma unroll
            for (int c = 0; c < 8; ++c) { s += acc[i][c]; s2 += acc[i][c] * acc[i][c]; }
            *(uint4*)&sx[(pl0 + i) * 136 + g * 16 + sub * 8] = make_uint4(pk[0],pk[1],pk[2],pk[3]);
            sred [(pl0 + i) * 20 + gy] = s;
            sred2[(pl0 + i) * 20 + gy] = s2;
        }
    }
    __syncthreads();   // inv tile + partials complete (swg dead from here)

    // ======== Phase C: MLP (4 hidden chunks of 128, double-buffered sh, 1 barrier/chunk) ====
    // per-lane LN stats straight from sred (no reduction barrier)
    float mu_r[4], rs_r[4];
    #pragma unroll
    for (int tn = 0; tn < 4; ++tn) {
        int px = tn * 16 + ln15;
        float s = 0.f, s2 = 0.f;
        #pragma unroll
        for (int k4 = 0; k4 < 4; ++k4) {
            float4 a = *(const float4*)&sred [px * 20 + k4 * 4];
            float4 c = *(const float4*)&sred2[px * 20 + k4 * 4];
            s  += a.x + a.y + a.z + a.w;
            s2 += c.x + c.y + c.z + c.w;
        }
        float m = s * (1.f / 128.f);
        mu_r[tn] = m;
        rs_r[tn] = rsqrtf(s2 * (1.f / 128.f) - m * m + 1e-6f);
    }

    f32x4 acc2[4][2];
    #pragma unroll
    for (int i = 0; i < 4; ++i)
        #pragma unroll
        for (int j = 0; j < 2; ++j) acc2[i][j] = (f32x4)0.f;

    #pragma unroll
    for (int j = 0; j < 4; ++j) {
        short* shc = (j & 1) ? sh1b : sh0;          // this chunk's H buffer
        short* shp = (j & 1) ? sh0  : sh1b;         // previous chunk's H buffer
        // issue this chunk's A-frags and (if j>0) previous chunk's B-frags together
        short8 a1f[4][2];
        #pragma unroll
        for (int k4 = 0; k4 < 4; ++k4)
            #pragma unroll
            for (int tm = 0; tm < 2; ++tm)
                a1f[k4][tm] = *(const short8*)&lw1b[(size_t)(j * 128 + wv * 32 + tm * 16 + ln15) * 128 + k4 * 32 + quad * 8];
        if (j > 0) {
            short8 bq[4][2];
            #pragma unroll
            for (int k4 = 0; k4 < 4; ++k4)
                #pragma unroll
                for (int tn = 0; tn < 2; ++tn)
                    bq[k4][tn] = *(const short8*)&w2b[(size_t)(wv * 32 + tn * 16 + ln15) * 512 + (j - 1) * 128 + k4 * 32 + quad * 8];
            // phase 2 of chunk j-1 (hides a1f latency)
            #pragma unroll
            for (int k4 = 0; k4 < 4; ++k4) {
                short8 af[4];
                #pragma unroll
                for (int tm = 0; tm < 4; ++tm)
                    af[tm] = *(const short8*)&shp[(tm * 16 + ln15) * 136 + k4 * 32 + quad * 8];
                #pragma unroll
                for (int tm = 0; tm < 4; ++tm)
                    #pragma unroll
                    for (int tn = 0; tn < 2; ++tn)
                        acc2[tm][tn] = __builtin_amdgcn_mfma_f32_16x16x32_bf16(af[tm], bq[k4][tn], acc2[tm][tn], 0, 0, 0);
            }
        }
        // phase 1 of chunk j
        f32x4 acc1[2][4];
        #pragma unroll
        for (int tm = 0; tm < 2; ++tm)
            #pragma unroll
            for (int tn = 0; tn < 4; ++tn) acc1[tm][tn] = (f32x4)0.f;
        #pragma unroll
        for (int k4 = 0; k4 < 4; ++k4) {
            short8 bf[4];
            #pragma unroll
            for (int tn = 0; tn < 4; ++tn)
                bf[tn] = *(const short8*)&sx[(tn * 16 + ln15) * 136 + k4 * 32 + quad * 8];
            #pragma unroll
            for (int tm = 0; tm < 2; ++tm)
                #pragma unroll
                for (int tn = 0; tn < 4; ++tn)
                    acc1[tm][tn] = __builtin_amdgcn_mfma_f32_16x16x32_bf16(a1f[k4][tm], bf[tn], acc1[tm][tn], 0, 0, 0);
        }
        // LN + GELU -> shc
        #pragma unroll
        for (int tm = 0; tm < 2; ++tm) {
            int nl = wv * 32 + tm * 16 + quad * 4;
            int n  = j * 128 + nl;
            float4 s14 = *(const float4*)&s1[n];
            float4 t14 = *(const float4*)&t1[n];
            #pragma unroll
            for (int tn = 0; tn < 4; ++tn) {
                int px = tn * 16 + ln15;
                float g0 = gelu_t(rs_r[tn] * (acc1[tm][tn][0] - mu_r[tn] * s14.x) + t14.x);
                float g1 = gelu_t(rs_r[tn] * (acc1[tm][tn][1] - mu_r[tn] * s14.y) + t14.y);
                float g2 = gelu_t(rs_r[tn] * (acc1[tm][tn][2] - mu_r[tn] * s14.z) + t14.z);
                float g3 = gelu_t(rs_r[tn] * (acc1[tm][tn][3] - mu_r[tn] * s14.w) + t14.w);
                uint2 pk;
                pk.x = f2b(g0) | (f2b(g1) << 16);
                pk.y = f2b(g2) | (f2b(g3) << 16);
                *(uint2*)&shc[px * 136 + nl] = pk;
            }
        }
        __syncthreads();   // H(j) complete; next iteration may read shc and overwrite shp
    }
    // final phase 2 (chunk 3) from sh1b
    {
        short8 bq[4][2];
        #pragma unroll
        for (int k4 = 0; k4 < 4; ++k4)
            #pragma unroll
            for (int tn = 0; tn < 2; ++tn)
                bq[k4][tn] = *(const short8*)&w2b[(size_t)(wv * 32 + tn * 16 + ln15) * 512 + 3 * 128 + k4 * 32 + quad * 8];
        #pragma unroll
        for (int k4 = 0; k4 < 4; ++k4) {
            short8 af[4];
            #pragma unroll
            for (int tm = 0; tm < 4; ++tm)
                af[tm] = *(const short8*)&sh1b[(tm * 16 + ln15) * 136 + k4 * 32 + quad * 8];
            #pragma unroll
            for (int tm = 0; tm < 4; ++tm)
                #pragma unroll
                for (int tn = 0; tn < 2; ++tn)
                    acc2[tm][tn] = __builtin_amdgcn_mfma_f32_16x16x32_bf16(af[tm], bq[k4][tn], acc2[tm][tn], 0, 0, 0);
        }
    }

    // ======== final epilogue: +b2 +residual, fp32 channels-first float4 ========
    #pragma unroll
    for (int tm = 0; tm < 4; ++tm) {
        int p = p0i + tm * 16 + quad * 4;
        #pragma unroll
        for (int tn = 0; tn < 2; ++tn) {
            int c = wv * 32 + tn * 16 + ln15;
            size_t base = ((size_t)b * CIN + c) * HW + p;
            float bj = b2[c];
            float4 rv = *(const float4*)&x[base];
            float4 ov = make_float4(acc2[tm][tn][0] + bj + rv.x,
                                    acc2[tm][tn][1] + bj + rv.y,
                                    acc2[tm][tn][2] + bj + rv.z,
                                    acc2[tm][tn][3] + bj + rv.w);
            *(float4*)&outp[base] = ov;
        }
    }
}

extern "C" void kernel_launch(void* const* d_in, const int* in_sizes, int n_in,
                              void* d_out, int out_size, void* d_ws, size_t ws_size,
                              hipStream_t stream) {
    const float* x       = (const float*)d_in[0];
    const float* conv1_w = (const float*)d_in[1];
    const float* conv1_b = (const float*)d_in[2];
    const float* bn_g    = (const float*)d_in[3];
    const float* bn_b    = (const float*)d_in[4];
    const float* bn_m    = (const float*)d_in[5];
    const float* bn_v    = (const float*)d_in[6];
    const float* conv2_w = (const float*)d_in[7];
    const float* conv2_b = (const float*)d_in[8];
    const float* ln_w    = (const float*)d_in[9];
    const float* ln_b    = (const float*)d_in[10];
    const float* w1      = (const float*)d_in[11];
    const float* b1      = (const float*)d_in[12];
    const float* w2      = (const float*)d_in[13];
    const float* b2      = (const float*)d_in[14];
    float* out = (float*)d_out;

    float* F = (float*)d_ws;
    float* sc1  = F;                 // 32
    float* sh1  = F + 32;            // 32
    float* s1   = F + 64;            // 512
    float* t1   = F + 576;           // 512
    ushort_t* S    = (ushort_t*)(F + 1088);
    ushort_t* c1b  = S;              // 4096
    ushort_t* c2b  = c1b + 4096;     // 12800 (400x32, zero-padded)
    ushort_t* lw1b = c2b + 12800;    // 65536
    ushort_t* w2b  = lw1b + 65536;   // 65536

    k_prep <<<256, 256, 0, stream>>>(conv1_w, conv1_b, bn_g, bn_b, bn_m, bn_v,
                                     conv2_w, ln_w, w1, w2, c1b, c2b, lw1b, w2b, sc1, sh1);
    k_prep2<<<1, 512, 0, stream>>>(w1, ln_w, ln_b, b1, s1, t1);
    k_mega <<<392, 256, 0, stream>>>(x, (const short*)c1b, (const short*)c2b,
                                     sc1, sh1, conv2_b, lw1b, w2b, s1, t1, b2, out);
}